// Round 4
// baseline (623.462 us; speedup 1.0000x reference)
//
#include <hip/hip_runtime.h>
#include <math.h>

#define B_SZ 256
#define N_TOKENS 196
#define DIM 384
#define NH 8
#define QKV_ST 1536      // NH*(2*32+128)
#define HID 1536
#define CTX_ST 1024      // NH*128
#define VT_ST 224        // padded token stride of V^T (14*16, 448B = 7 cache lines)
#define BT_ST 208        // bias table m-stride (13*16)

typedef short s16x8_base __attribute__((ext_vector_type(8)));
typedef s16x8_base __attribute__((may_alias)) s16x8;
typedef float f32x4_base __attribute__((ext_vector_type(4)));
typedef f32x4_base __attribute__((may_alias)) f32x4;

typedef const __attribute__((address_space(1))) unsigned int* gp_t;
typedef __attribute__((address_space(3))) unsigned int* lp_t;
__device__ __forceinline__ void async16(const void* g, void* l) {
  __builtin_amdgcn_global_load_lds((gp_t)g, (lp_t)l, 16, 0, 0);
}

__device__ inline unsigned short f2b(float f) {
  union { float f; unsigned int u; } v; v.f = f;
  unsigned int r = (v.u + 0x7FFFu + ((v.u >> 16) & 1u)) >> 16;   // RNE, finite inputs
  return (unsigned short)r;
}

// ---------------- fp32 -> bf16 convert ----------------
__global__ __launch_bounds__(256)
void cvt_f32_bf16(const float* __restrict__ in, unsigned short* __restrict__ out, int n4) {
  int i = blockIdx.x * 256 + threadIdx.x;
  const int stride = gridDim.x * 256;
  for (; i < n4; i += stride) {
    float4 v = ((const float4*)in)[i];
    ushort4 o;
    o.x = f2b(v.x); o.y = f2b(v.y); o.z = f2b(v.z); o.w = f2b(v.w);
    ((ushort4*)out)[i] = o;
  }
}

// ---------------- fused bias table: biasT[h][n][m(208)] = ab[h][bidx[n][min(m,195)]] ----------------
__global__ __launch_bounds__(256)
void build_bias(const float* __restrict__ ab, const int* __restrict__ bidx,
                float* __restrict__ bT) {
  int i = blockIdx.x * 256 + threadIdx.x;
  if (i >= NH * N_TOKENS * BT_ST) return;
  int m = i % BT_ST;
  int n = (i / BT_ST) % N_TOKENS;
  int h = i / (BT_ST * N_TOKENS);
  int mc = m < N_TOKENS ? m : N_TOKENS - 1;
  bT[i] = ab[h * N_TOKENS + bidx[n * N_TOKENS + mc]];
}

// ---------------- bf16 MFMA GEMM: C[M][N] = A[M][K] @ B[N][K]^T + bias ----------------
// 128x128 tile, BK=32, 256 threads; staging via global_load_lds width=16.
template <int OUT_BF16>
__global__ __launch_bounds__(256)
void gemm_bf16_bt(const unsigned short* __restrict__ A,
                  const unsigned short* __restrict__ Bm,
                  const float* __restrict__ bias,
                  void* __restrict__ C, int M, int N, int K) {
  __shared__ unsigned short As[128][32];
  __shared__ unsigned short Bs[128][32];
  const int tid = threadIdx.x;
  const int lane = tid & 63, wave = tid >> 6;
  const int quad = lane >> 4, l15 = lane & 15;
  const int ntile = N >> 7;
  const int bx = blockIdx.x % ntile, by = blockIdx.x / ntile;
  const int row0 = by << 7, col0 = bx << 7;

  // global_load_lds staging: wave w fills LDS chunks w and w+4 of each tile
  // (chunk = 16 rows x 64B = 1KB; lane L -> row chunk*16 + L/4, col (L&3)*16B)
  const int sr = lane >> 2;
  const int sc = (lane & 3) << 3;   // shorts
  const unsigned short* Ag0 = A + (size_t)(row0 + wave * 16 + sr) * K + sc;
  const unsigned short* Ag1 = A + (size_t)(row0 + 64 + wave * 16 + sr) * K + sc;
  const unsigned short* Bg0 = Bm + (size_t)(col0 + wave * 16 + sr) * K + sc;
  const unsigned short* Bg1 = Bm + (size_t)(col0 + 64 + wave * 16 + sr) * K + sc;
  unsigned short* Al0 = &As[wave * 16][0];
  unsigned short* Al1 = &As[64 + wave * 16][0];
  unsigned short* Bl0 = &Bs[wave * 16][0];
  unsigned short* Bl1 = &Bs[64 + wave * 16][0];

  const int wr = (wave >> 1) << 6, wc = (wave & 1) << 6;

  f32x4 zero = {0.f, 0.f, 0.f, 0.f};
  f32x4 acc[4][4];
#pragma unroll
  for (int i = 0; i < 4; ++i)
#pragma unroll
    for (int j = 0; j < 4; ++j) acc[i][j] = zero;

  for (int k0 = 0; k0 < K; k0 += 32) {
    __syncthreads();                 // prev frags consumed
    async16(Ag0 + k0, Al0);
    async16(Ag1 + k0, Al1);
    async16(Bg0 + k0, Bl0);
    async16(Bg1 + k0, Bl1);
    __syncthreads();                 // vmcnt drained by barrier
    s16x8 af[4], bf[4];
#pragma unroll
    for (int i = 0; i < 4; ++i) {
      af[i] = *(const s16x8*)&As[wr + i * 16 + l15][quad * 8];
      bf[i] = *(const s16x8*)&Bs[wc + i * 16 + l15][quad * 8];
    }
#pragma unroll
    for (int i = 0; i < 4; ++i)
#pragma unroll
      for (int j = 0; j < 4; ++j)
        acc[i][j] = __builtin_amdgcn_mfma_f32_16x16x32_bf16(af[i], bf[j], acc[i][j], 0, 0, 0);
  }

#pragma unroll
  for (int j = 0; j < 4; ++j) {
    const int col = col0 + wc + j * 16 + l15;
    const float bj = bias[col];
#pragma unroll
    for (int i = 0; i < 4; ++i) {
      const int rowb = row0 + wr + i * 16 + quad * 4;
#pragma unroll
      for (int r = 0; r < 4; ++r) {
        float v = acc[i][j][r] + bj;
        if (OUT_BF16)
          ((unsigned short*)C)[(size_t)(rowb + r) * N + col] = f2b(v);
        else
          ((float*)C)[(size_t)(rowb + r) * N + col] = v;
      }
    }
  }
}

// ---------------- V -> V^T (per (b,h): [196][128] -> [128][224], pad zeros) ----------------
__global__ __launch_bounds__(256)
void transpose_v(const unsigned short* __restrict__ qkv, unsigned short* __restrict__ vt) {
  __shared__ unsigned short ts[32][36];
  const int id = blockIdx.x;
  const int tile = id % 28;
  const int bh = id / 28;
  const int b = bh >> 3, h = bh & 7;
  const int nt = tile % 7, dt = tile / 7;
  const int n0 = nt * 32, d0 = dt * 32;
  const int t = threadIdx.x;
  {
    const int nl = t >> 3, dq = (t & 7) << 2;
    ushort4 v4; v4.x = 0; v4.y = 0; v4.z = 0; v4.w = 0;
    if (n0 + nl < 196)
      v4 = *(const ushort4*)(qkv + ((size_t)(b * 196 + n0 + nl) * QKV_ST + h * 192 + 64 + d0 + dq));
    ts[dq + 0][nl] = v4.x; ts[dq + 1][nl] = v4.y;
    ts[dq + 2][nl] = v4.z; ts[dq + 3][nl] = v4.w;
  }
  __syncthreads();
  {
    const int dl = t >> 3, nq = (t & 7) << 2;
    ushort4 o;
    o.x = ts[dl][nq + 0]; o.y = ts[dl][nq + 1];
    o.z = ts[dl][nq + 2]; o.w = ts[dl][nq + 3];
    *(ushort4*)(vt + ((size_t)(bh * 128 + d0 + dl) * VT_ST + n0 + nq)) = o;
  }
}

// ---------------- MFMA attention: one block per (b,h), 2 barriers/chunk ----------------
__global__ __launch_bounds__(256, 3)
void attn_mfma(const unsigned short* __restrict__ qkv,
               const unsigned short* __restrict__ vt,
               const float* __restrict__ bT,
               unsigned short* __restrict__ ctx) {
  __shared__ unsigned short Pm[112][232];   // 52KB; stride 232 keeps b128 reads 16B-aligned
  __shared__ float inv_s[112];

  const int bh = blockIdx.x;
  const int b = bh >> 3, h = bh & 7;
  const int tid = threadIdx.x;
  const int lane = tid & 63, w = tid >> 6;
  const int quad = lane >> 4, l15 = lane & 15;
  const float scale = 0.17677669529663687f;

  const unsigned short* qbase = qkv + (size_t)b * N_TOKENS * QKV_ST + h * 192;
  const unsigned short* vbase = vt + (size_t)bh * 128 * VT_ST;
  const float* bTh = bT + (size_t)h * N_TOKENS * BT_ST;

  if (tid < 112) {
#pragma unroll
    for (int c = 208; c < 224; ++c) Pm[tid][c] = 0;   // zero pad cols read by PV ks=6
  }

  f32x4 zero = {0.f, 0.f, 0.f, 0.f};

  for (int chunk = 0; chunk < 2; ++chunk) {
    const int nbase = chunk * 112;
    __syncthreads();   // Pm/inv_s free from previous chunk; init visible

    // ---- S phase: wave w owns row-tiles {w*32, w*32+16} (wave 3: one) ----
    const int ntr = (w < 3) ? 2 : 1;
    for (int t2 = 0; t2 < ntr; ++t2) {
      const int rowt = w * 32 + t2 * 16;
      int nq = nbase + rowt + l15; nq = nq < 196 ? nq : 195;
      s16x8 aq = *(const s16x8*)(qbase + (size_t)nq * QKV_ST + quad * 8);
      f32x4 sacc[13];
#pragma unroll
      for (int j = 0; j < 13; ++j) {
        s16x8 bk = *(const s16x8*)(qbase + (size_t)(j * 16 + l15) * QKV_ST + 32 + quad * 8);
        sacc[j] = __builtin_amdgcn_mfma_f32_16x16x32_bf16(aq, bk, zero, 0, 0, 0);
      }
      int nrow[4];
#pragma unroll
      for (int r = 0; r < 4; ++r) {
        int n = nbase + rowt + quad * 4 + r;
        nrow[r] = n < 196 ? n : 195;
      }
      float mx[4] = {-1e30f, -1e30f, -1e30f, -1e30f};
#pragma unroll
      for (int j = 0; j < 13; ++j) {
        const int m = j * 16 + l15;
#pragma unroll
        for (int r = 0; r < 4; ++r) {
          float s = sacc[j][r] * scale + bTh[(size_t)nrow[r] * BT_ST + m];
          s = (m < 196) ? s : -1e30f;
          sacc[j][r] = s;
          mx[r] = fmaxf(mx[r], s);
        }
      }
#pragma unroll
      for (int o = 8; o > 0; o >>= 1)
#pragma unroll
        for (int r = 0; r < 4; ++r) mx[r] = fmaxf(mx[r], __shfl_xor(mx[r], o));
      float sm[4] = {0.f, 0.f, 0.f, 0.f};
#pragma unroll
      for (int j = 0; j < 13; ++j)
#pragma unroll
        for (int r = 0; r < 4; ++r) {
          float e = __expf(sacc[j][r] - mx[r]);
          sm[r] += e;
          Pm[rowt + quad * 4 + r][j * 16 + l15] = f2b(e);
        }
#pragma unroll
      for (int o = 8; o > 0; o >>= 1)
#pragma unroll
        for (int r = 0; r < 4; ++r) sm[r] += __shfl_xor(sm[r], o);
      if (l15 == 0) {
#pragma unroll
        for (int r = 0; r < 4; ++r) inv_s[rowt + quad * 4 + r] = 1.f / sm[r];
      }
    }

    // ---- PV: wave w owns d-cols [w*32, w*32+32); B-frags direct from global ----
    f32x4 pacc[7][2];
#pragma unroll
    for (int i = 0; i < 7; ++i) { pacc[i][0] = zero; pacc[i][1] = zero; }

    const unsigned short* vr0 = vbase + (size_t)(w * 32 + l15) * VT_ST + quad * 8;
    const unsigned short* vr1 = vr0 + 16 * VT_ST;
    s16x8 nb0 = *(const s16x8*)vr0;
    s16x8 nb1 = *(const s16x8*)vr1;
    __syncthreads();   // P + inv_s visible to all waves

    for (int ks = 0; ks < 7; ++ks) {
      s16x8 cb0 = nb0, cb1 = nb1;
      if (ks < 6) {
        nb0 = *(const s16x8*)(vr0 + (ks + 1) * 32);
        nb1 = *(const s16x8*)(vr1 + (ks + 1) * 32);
      }
#pragma unroll
      for (int i = 0; i < 7; ++i) {
        s16x8 ap = *(const s16x8*)&Pm[i * 16 + l15][ks * 32 + quad * 8];
        pacc[i][0] = __builtin_amdgcn_mfma_f32_16x16x32_bf16(ap, cb0, pacc[i][0], 0, 0, 0);
        pacc[i][1] = __builtin_amdgcn_mfma_f32_16x16x32_bf16(ap, cb1, pacc[i][1], 0, 0, 0);
      }
    }

    // ---- epilogue: normalize + store (bf16 ctx) ----
#pragma unroll
    for (int i = 0; i < 7; ++i) {
#pragma unroll
      for (int jl = 0; jl < 2; ++jl) {
        const int d = w * 32 + jl * 16 + l15;
#pragma unroll
        for (int r = 0; r < 4; ++r) {
          const int nl_ = i * 16 + quad * 4 + r;
          const int n = nbase + nl_;
          if (n < 196) {
            ctx[(size_t)(b * N_TOKENS + n) * CTX_ST + h * 128 + d] =
                f2b(pacc[i][jl][r] * inv_s[nl_]);
          }
        }
      }
    }
  }
}

extern "C" void kernel_launch(void* const* d_in, const int* in_sizes, int n_in,
                              void* d_out, int out_size, void* d_ws, size_t ws_size,
                              hipStream_t stream) {
  const float* x     = (const float*)d_in[0];
  const float* Wqkv  = (const float*)d_in[1];
  const float* bqkv  = (const float*)d_in[2];
  const float* Wproj = (const float*)d_in[3];
  const float* bproj = (const float*)d_in[4];
  const float* ab    = (const float*)d_in[5];
  const int*   bidx  = (const int*)d_in[6];
  float* out = (float*)d_out;

  const size_t szWq = 589824, szWp = 393216, szX = (size_t)B_SZ * N_TOKENS * DIM;
  const size_t szBT = (size_t)NH * N_TOKENS * BT_ST;                  // floats
  const size_t fixedB = (szWq + szWp + szX) * 2 + szBT * 4;
  // per-batch elements (bf16): vt 8*128*224, qkv 196*1536, ctx 196*1024
  const size_t perB = (229376ULL + 301056ULL + 200704ULL) * 2;
  int Bs = 256;
  while (Bs > 32 && fixedB + (size_t)Bs * perB > ws_size) Bs >>= 1;

  unsigned short* Wqb  = (unsigned short*)d_ws;
  unsigned short* Wpb  = Wqb + szWq;
  unsigned short* xb   = Wpb + szWp;
  float*          bTb  = (float*)(xb + szX);
  unsigned short* vtb  = (unsigned short*)(bTb + szBT);
  unsigned short* qkvb = vtb + (size_t)Bs * 229376;
  unsigned short* ctxb = qkvb + (size_t)Bs * 301056;

  cvt_f32_bf16<<<dim3(576), dim3(256), 0, stream>>>(Wqkv, Wqb, (int)(szWq / 4));
  cvt_f32_bf16<<<dim3(384), dim3(256), 0, stream>>>(Wproj, Wpb, (int)(szWp / 4));
  cvt_f32_bf16<<<dim3(4096), dim3(256), 0, stream>>>(x, xb, (int)(szX / 4));
  build_bias<<<dim3((NH * N_TOKENS * BT_ST + 255) / 256), dim3(256), 0, stream>>>(ab, bidx, bTb);

  const int nslice = B_SZ / Bs;
  const int Ms = Bs * N_TOKENS;
  for (int s = 0; s < nslice; ++s) {
    const unsigned short* xs = xb + (size_t)s * Ms * DIM;
    float* outs = out + (size_t)s * Ms * DIM;
    gemm_bf16_bt<1><<<dim3((Ms / 128) * (HID / 128)), dim3(256), 0, stream>>>(
        xs, Wqb, bqkv, qkvb, Ms, HID, DIM);
    transpose_v<<<dim3(Bs * 8 * 28), dim3(256), 0, stream>>>(qkvb, vtb);
    attn_mfma<<<dim3(Bs * 8), dim3(256), 0, stream>>>(qkvb, vtb, bTb, ctxb);
    gemm_bf16_bt<0><<<dim3((Ms / 128) * (DIM / 128)), dim3(256), 0, stream>>>(
        ctxb, Wpb, bproj, outs, Ms, DIM, CTX_ST);
  }
}